// Round 6
// baseline (126.329 us; speedup 1.0000x reference)
//
#include <hip/hip_runtime.h>
#include <hip/hip_bf16.h>

#define G_ 64
#define N_ 1024
#define DIN 128
#define DH 256
#define DOUT 10

typedef float floatx4 __attribute__((ext_vector_type(4)));
typedef short shortx8 __attribute__((ext_vector_type(8)));

__device__ __forceinline__ ushort f2bf(float f) {
  unsigned u = __builtin_bit_cast(unsigned, f);
  unsigned r = (u + 0x7FFFu + ((u >> 16) & 1u)) >> 16;   // RNE
  return (ushort)r;
}
__device__ __forceinline__ float bflo(unsigned q) {
  return __builtin_bit_cast(float, q << 16);
}
__device__ __forceinline__ float bfhi(unsigned q) {
  return __builtin_bit_cast(float, q & 0xFFFF0000u);
}

// ---------------------------------------------------------------------------
// k1: blocks 0..1023 — 64 nodes each: norminv + xb (bf16) + per-block u
//   partial. blocks 1024..1087 — W1 -> w1t bf16 (B^T); block 1087 also zeroes
//   the per-graph completion counters used by k2's fused head.
// ---------------------------------------------------------------------------
__global__ __launch_bounds__(256) void k1_fused(
    const float* __restrict__ x, const float* __restrict__ W1,
    float* __restrict__ norminv, float* __restrict__ u_part,
    ushort* __restrict__ xb, ushort* __restrict__ w1t,
    unsigned* __restrict__ cnt) {
  if (blockIdx.x >= 1024) {            // W1 transpose+convert tail (64 KB)
    const int wb = blockIdx.x - 1024;
    if (wb == 63 && threadIdx.x < G_) cnt[threadIdx.x] = 0;  // re-init counters
    #pragma unroll
    for (int i = 0; i < 2; ++i) {
      const int idx = wb * 512 + i * 256 + threadIdx.x;   // 0..32767
      const int k = idx >> 8, d = idx & 255;
      w1t[d * DIN + k] = f2bf(W1[k * DH + d]);
    }
    return;
  }
  const int tid = threadIdx.x;
  const int wave = tid >> 6;
  const int lane = tid & 63;
  const int half = lane >> 5;          // which node of the pair
  const int l32 = lane & 31;           // d-quad index (d = l32*4..+3)
  __shared__ float red[8][DIN];        // 8 half-waves x 128 d
  float a0 = 0.f, a1 = 0.f, a2 = 0.f, a3 = 0.f;
  const int mbase = blockIdx.x * 64 + wave * 16;
  #pragma unroll
  for (int i = 0; i < 8; ++i) {
    const int m = mbase + i * 2 + half;
    const float4 v = ((const float4*)(x + (size_t)m * DIN))[l32];
    float ss = v.x * v.x + v.y * v.y + v.z * v.z + v.w * v.w;
    #pragma unroll
    for (int off = 16; off; off >>= 1) ss += __shfl_xor(ss, off, 64);
    const float ninv = rsqrtf(ss + 1e-24f);
    if (l32 == 0) norminv[m] = ninv;
    uint2 pk;
    pk.x = (unsigned)f2bf(v.x) | ((unsigned)f2bf(v.y) << 16);
    pk.y = (unsigned)f2bf(v.z) | ((unsigned)f2bf(v.w) << 16);
    ((uint2*)(xb + (size_t)m * DIN))[l32] = pk;
    a0 = fmaf(v.x, ninv, a0);
    a1 = fmaf(v.y, ninv, a1);
    a2 = fmaf(v.z, ninv, a2);
    a3 = fmaf(v.w, ninv, a3);
  }
  *(float4*)&red[tid >> 5][l32 * 4] = make_float4(a0, a1, a2, a3);
  __syncthreads();
  if (tid < DIN) {
    float t = 0.f;
    #pragma unroll
    for (int r = 0; r < 8; ++r) t += red[r][tid];
    u_part[blockIdx.x * DIN + tid] = t;   // race-free per-block partial
  }
}

// ---------------------------------------------------------------------------
// k2: 256 blocks, 256 nodes each (g = blk>>2, quarter = blk&3).
// Prologue (u-sum, B-frags) amortized over 16 m-tiles (4x fewer blocks than
// R5). Stores hw_part[blk][d]; the LAST block of each graph (device-scope
// atomic counter) runs the fused head: sum 4 partials -> W2 GEMV ->
// log_softmax -> out. No separate k3 dispatch.
// ---------------------------------------------------------------------------
__global__ __launch_bounds__(256) void k2_mfma(
    const ushort* __restrict__ xb, const ushort* __restrict__ w1t,
    const float* __restrict__ b1, const float* __restrict__ norminv,
    const float* __restrict__ u_part, const float* __restrict__ W2,
    const float* __restrict__ b2, float* __restrict__ hw_part,
    unsigned* __restrict__ cnt, float* __restrict__ out) {
  const int gb = blockIdx.x;           // 0..255
  const int g = gb >> 2;
  const int mb0 = (gb & 3) << 8;       // first node (in-graph) of this quarter
  const int tid = threadIdx.x;
  const int lane = tid & 63;
  const int wave = tid >> 6;
  const int quad = lane >> 4;
  const int l16 = lane & 15;
  __shared__ float u_lds[DIN];
  __shared__ float s_lds[256];
  __shared__ unsigned last_flag;

  if (tid < DIN) {                      // u = sum of 16 k1-block partials
    float t = 0.f;
    const float* up = u_part + (size_t)(g << 4) * DIN + tid;
    #pragma unroll
    for (int r = 0; r < 16; ++r) t += up[r * DIN];
    u_lds[tid] = t;
  }
  // B-frags + bias hoisted once per block (global-load latency overlaps the
  // s-phase below). B[k][n]: n=l16, k=quad*8+j.
  shortx8 bfr[4][4];   // [dt][kt]
  float b1v[4];
  #pragma unroll
  for (int dt = 0; dt < 4; ++dt) {
    const int d = (wave << 6) + (dt << 4) + l16;
    b1v[dt] = b1[d];
    #pragma unroll
    for (int kt = 0; kt < 4; ++kt)
      bfr[dt][kt] = *(const shortx8*)(w1t + (size_t)d * DIN + (kt << 5) + (quad << 3));
  }
  __syncthreads();

  // s[m] = ninv[m]*(u . x[m]) - 1 for 256 nodes; 4 threads/node, 4 sub-tiles
  #pragma unroll
  for (int st = 0; st < 4; ++st) {
    const int nd = tid >> 2;
    const int qq = tid & 3;
    const size_t m = (size_t)(g << 10) + mb0 + (st << 6) + nd;
    const uint4* xr = (const uint4*)(xb + m * DIN + qq * 32);
    float p = 0.f;
    #pragma unroll
    for (int j = 0; j < 4; ++j) {
      const uint4 q = xr[j];
      const float* ub = &u_lds[qq * 32 + j * 8];
      p = fmaf(bflo(q.x), ub[0], p); p = fmaf(bfhi(q.x), ub[1], p);
      p = fmaf(bflo(q.y), ub[2], p); p = fmaf(bfhi(q.y), ub[3], p);
      p = fmaf(bflo(q.z), ub[4], p); p = fmaf(bfhi(q.z), ub[5], p);
      p = fmaf(bflo(q.w), ub[6], p); p = fmaf(bfhi(q.w), ub[7], p);
    }
    p += __shfl_xor(p, 1, 64);
    p += __shfl_xor(p, 2, 64);
    if (qq == 0) s_lds[(st << 6) + nd] = p * norminv[m] - 1.0f;
  }
  __syncthreads();

  float wsum[4] = {0.f, 0.f, 0.f, 0.f};
  #pragma unroll
  for (int mt = 0; mt < 16; ++mt) {
    // A-frags: A[m][k]: m=l16, k=quad*8+j (16B contiguous per lane)
    const ushort* ar = xb + ((size_t)(g << 10) + mb0 + (mt << 4) + l16) * DIN;
    shortx8 af[4];
    #pragma unroll
    for (int kt = 0; kt < 4; ++kt)
      af[kt] = *(const shortx8*)(ar + (kt << 5) + (quad << 3));

    floatx4 acc[4] = {{0.f, 0.f, 0.f, 0.f}, {0.f, 0.f, 0.f, 0.f},
                      {0.f, 0.f, 0.f, 0.f}, {0.f, 0.f, 0.f, 0.f}};
    #pragma unroll
    for (int kt = 0; kt < 4; ++kt)
      #pragma unroll
      for (int dt = 0; dt < 4; ++dt)
        acc[dt] = __builtin_amdgcn_mfma_f32_16x16x32_bf16(af[kt], bfr[dt][kt],
                                                          acc[dt], 0, 0, 0);
    // bias + relu + s-weight; C layout: row(m) = quad*4+r, col(d) = l16
    #pragma unroll
    for (int dt = 0; dt < 4; ++dt) {
      float bs = 0.f;
      #pragma unroll
      for (int r = 0; r < 4; ++r) {
        const float h = fmaxf(acc[dt][r] + b1v[dt], 0.f);
        bs = fmaf(s_lds[(mt << 4) + (quad << 2) + r], h, bs);
      }
      wsum[dt] += bs;
    }
  }
  #pragma unroll
  for (int dt = 0; dt < 4; ++dt) {
    float w = wsum[dt];
    w += __shfl_xor(w, 16, 64);
    w += __shfl_xor(w, 32, 64);
    if (quad == 0)
      hw_part[(size_t)gb * DH + (wave << 6) + (dt << 4) + l16] = w;
  }

  // ---- fused head: last block of this graph wins ---------------------------
  __threadfence();                          // release hw_part stores
  if (tid == 0) last_flag = (atomicAdd(&cnt[g], 1u) == 3u) ? 1u : 0u;
  __syncthreads();
  if (!last_flag) return;
  __threadfence();                          // acquire other blocks' stores

  __shared__ float w2l[DH * DOUT];          // 10 KB, coalesced stage
  __shared__ float hsum[DH];
  __shared__ float partial[40];
  __shared__ float p[DOUT];
  #pragma unroll
  for (int i = 0; i < (DH * DOUT) / 256; ++i)
    w2l[i * 256 + tid] = W2[i * 256 + tid];
  {
    float hs = 0.f;
    const float* hp = hw_part + (size_t)(g << 2) * DH + tid;
    #pragma unroll
    for (int r = 0; r < 4; ++r) hs += hp[r * DH];
    hsum[tid] = hs;
  }
  __syncthreads();
  if (tid < 40) {
    const int c = tid % 10, q = tid / 10;
    const float* hg = hsum + q * 64;
    const float* wg = w2l + (q * 64) * DOUT + c;
    float a = 0.f;
    #pragma unroll
    for (int k = 0; k < 64; ++k) a = fmaf(hg[k], wg[k * DOUT], a);
    partial[tid] = a;
  }
  __syncthreads();
  if (tid < DOUT) {
    p[tid] = (partial[tid] + partial[tid + 10] + partial[tid + 20] +
              partial[tid + 30]) * (1.0f / N_) + b2[tid];
  }
  __syncthreads();
  if (tid < DOUT) {
    float mx = p[0];
    #pragma unroll
    for (int c = 1; c < DOUT; ++c) mx = fmaxf(mx, p[c]);
    float se = 0.f;
    #pragma unroll
    for (int c = 0; c < DOUT; ++c) se += expf(p[c] - mx);
    out[g * DOUT + tid] = p[tid] - (mx + logf(se));
  }
}

extern "C" void kernel_launch(void* const* d_in, const int* in_sizes, int n_in,
                              void* d_out, int out_size, void* d_ws, size_t ws_size,
                              hipStream_t stream) {
  const float* x  = (const float*)d_in[0];
  // d_in[1] = batch (sorted, equal-sized) -> unused
  const float* W1 = (const float*)d_in[2];
  const float* b1 = (const float*)d_in[3];
  const float* W2 = (const float*)d_in[4];
  const float* b2 = (const float*)d_in[5];
  float* out = (float*)d_out;

  // ws (floats): u_part[1024*128] hw_part[256*256] norminv[65536]; bf16 blobs;
  // then per-graph counters.
  float* u_part  = (float*)d_ws;
  float* hw_part = u_part + 1024 * DIN;
  float* norminv = hw_part + 256 * DH;
  ushort* xb  = (ushort*)(norminv + (size_t)G_ * N_);   // [65536][128] bf16
  ushort* w1t = xb + (size_t)G_ * N_ * DIN;             // [256][128] bf16
  unsigned* cnt = (unsigned*)(w1t + DH * DIN);          // [64] counters

  // Every ws location is written before it is read -> no memset, no atomics
  // needing pre-zero (cnt is zeroed by k1's tail block each call).
  k1_fused<<<1024 + 64, 256, 0, stream>>>(x, W1, norminv, u_part, xb, w1t, cnt);
  k2_mfma<<<256, 256, 0, stream>>>(xb, w1t, b1, norminv, u_part, W2, b2,
                                   hw_part, cnt, out);
}

// Round 7
// 111.898 us; speedup vs baseline: 1.1290x; 1.1290x over previous
//
#include <hip/hip_runtime.h>
#include <hip/hip_bf16.h>

#define G_ 64
#define N_ 1024
#define DIN 128
#define DH 256
#define DOUT 10

typedef float floatx4 __attribute__((ext_vector_type(4)));
typedef short shortx8 __attribute__((ext_vector_type(8)));

__device__ __forceinline__ ushort f2bf(float f) {
  unsigned u = __builtin_bit_cast(unsigned, f);
  unsigned r = (u + 0x7FFFu + ((u >> 16) & 1u)) >> 16;   // RNE
  return (ushort)r;
}
__device__ __forceinline__ float bflo(unsigned q) {
  return __builtin_bit_cast(float, q << 16);
}
__device__ __forceinline__ float bfhi(unsigned q) {
  return __builtin_bit_cast(float, q & 0xFFFF0000u);
}

// ---------------------------------------------------------------------------
// k1: blocks 0..1023 — 64 nodes each: norminv + xb (bf16) + per-block u
//   partial. blocks 1024..1087 — W1 -> w1t bf16 (B^T).   (proven R5 version)
// ---------------------------------------------------------------------------
__global__ __launch_bounds__(256) void k1_fused(
    const float* __restrict__ x, const float* __restrict__ W1,
    float* __restrict__ norminv, float* __restrict__ u_part,
    ushort* __restrict__ xb, ushort* __restrict__ w1t) {
  if (blockIdx.x >= 1024) {            // W1 transpose+convert tail (64 KB)
    const int wb = blockIdx.x - 1024;
    #pragma unroll
    for (int i = 0; i < 2; ++i) {
      const int idx = wb * 512 + i * 256 + threadIdx.x;   // 0..32767
      const int k = idx >> 8, d = idx & 255;
      w1t[d * DIN + k] = f2bf(W1[k * DH + d]);
    }
    return;
  }
  const int tid = threadIdx.x;
  const int wave = tid >> 6;
  const int lane = tid & 63;
  const int half = lane >> 5;          // which node of the pair
  const int l32 = lane & 31;           // d-quad index (d = l32*4..+3)
  __shared__ float red[8][DIN];        // 8 half-waves x 128 d
  float a0 = 0.f, a1 = 0.f, a2 = 0.f, a3 = 0.f;
  const int mbase = blockIdx.x * 64 + wave * 16;
  #pragma unroll
  for (int i = 0; i < 8; ++i) {
    const int m = mbase + i * 2 + half;
    const float4 v = ((const float4*)(x + (size_t)m * DIN))[l32];
    float ss = v.x * v.x + v.y * v.y + v.z * v.z + v.w * v.w;
    #pragma unroll
    for (int off = 16; off; off >>= 1) ss += __shfl_xor(ss, off, 64);
    const float ninv = rsqrtf(ss + 1e-24f);
    if (l32 == 0) norminv[m] = ninv;
    uint2 pk;
    pk.x = (unsigned)f2bf(v.x) | ((unsigned)f2bf(v.y) << 16);
    pk.y = (unsigned)f2bf(v.z) | ((unsigned)f2bf(v.w) << 16);
    ((uint2*)(xb + (size_t)m * DIN))[l32] = pk;
    a0 = fmaf(v.x, ninv, a0);
    a1 = fmaf(v.y, ninv, a1);
    a2 = fmaf(v.z, ninv, a2);
    a3 = fmaf(v.w, ninv, a3);
  }
  *(float4*)&red[tid >> 5][l32 * 4] = make_float4(a0, a1, a2, a3);
  __syncthreads();
  if (tid < DIN) {
    float t = 0.f;
    #pragma unroll
    for (int r = 0; r < 8; ++r) t += red[r][tid];
    u_part[blockIdx.x * DIN + tid] = t;   // race-free per-block partial
  }
}

// ---------------------------------------------------------------------------
// k1b: s[m] = ninv[m]*(u . x[m]) - 1 for all 65536 nodes.
// 1024 blocks x 256 thr; 64 nodes/block, 4 threads/node. Two latency
// batches total (u-partial sum, then xb dot reads). Hoisted out of k2 so the
// MFMA kernel has no serial prologue.
// ---------------------------------------------------------------------------
__global__ __launch_bounds__(256) void k1b_s(
    const ushort* __restrict__ xb, const float* __restrict__ norminv,
    const float* __restrict__ u_part, float* __restrict__ s) {
  const int blk = blockIdx.x;
  const int g = blk >> 4;
  const int mb = (blk & 15) << 6;
  const int tid = threadIdx.x;
  __shared__ float u_lds[DIN];
  if (tid < DIN) {                      // u = sum of 16 k1-block partials
    float t = 0.f;
    const float* up = u_part + (size_t)(g << 4) * DIN + tid;
    #pragma unroll
    for (int r = 0; r < 16; ++r) t += up[r * DIN];
    u_lds[tid] = t;
  }
  __syncthreads();
  const int nd = tid >> 2;              // 0..63
  const int qq = tid & 3;
  const size_t m = (size_t)(g << 10) + mb + nd;
  const uint4* xr = (const uint4*)(xb + m * DIN + qq * 32);
  float p = 0.f;
  #pragma unroll
  for (int j = 0; j < 4; ++j) {
    const uint4 q = xr[j];
    const float* ub = &u_lds[qq * 32 + j * 8];
    p = fmaf(bflo(q.x), ub[0], p); p = fmaf(bfhi(q.x), ub[1], p);
    p = fmaf(bflo(q.y), ub[2], p); p = fmaf(bfhi(q.y), ub[3], p);
    p = fmaf(bflo(q.z), ub[4], p); p = fmaf(bfhi(q.z), ub[5], p);
    p = fmaf(bflo(q.w), ub[6], p); p = fmaf(bfhi(q.w), ub[7], p);
  }
  p += __shfl_xor(p, 1, 64);
  p += __shfl_xor(p, 2, 64);
  if (qq == 0) s[m] = p * norminv[m] - 1.0f;
}

// ---------------------------------------------------------------------------
// k2: sync-free, LDS-free MFMA. 1024 blocks x 4 independent waves.
// Wave = 64 nodes x 64 d. All loads (16 B-frags || 16 A-frags || 4 s-float4
// || bias) are independent -> ~one latency batch, then 64 MFMAs + epilogue.
// hw_part[blk][d], blk = (g, 16 node-tiles)  — same shape k3 already consumes.
// ---------------------------------------------------------------------------
__global__ __launch_bounds__(256) void k2_mfma(
    const ushort* __restrict__ xb, const ushort* __restrict__ w1t,
    const float* __restrict__ b1, const float* __restrict__ s,
    float* __restrict__ hw_part) {
  const int blk = blockIdx.x;          // 0..1023
  const int g = blk >> 4;
  const int mb = (blk & 15) << 6;      // first node (in-graph)
  const int tid = threadIdx.x;
  const int lane = tid & 63;
  const int wave = tid >> 6;
  const int quad = lane >> 4;
  const int l16 = lane & 15;

  // B-frags + bias for this wave's 64-d slice. B[k][n]: n=l16, k=quad*8+j.
  shortx8 bfr[4][4];   // [dt][kt]
  float b1v[4];
  #pragma unroll
  for (int dt = 0; dt < 4; ++dt) {
    const int d = (wave << 6) + (dt << 4) + l16;
    b1v[dt] = b1[d];
    #pragma unroll
    for (int kt = 0; kt < 4; ++kt)
      bfr[dt][kt] =
          *(const shortx8*)(w1t + (size_t)d * DIN + (kt << 5) + (quad << 3));
  }
  // A-frags for 4 m-tiles. A[m][k]: m=l16, k=quad*8+j (16B contiguous/lane).
  shortx8 af[4][4];    // [mt][kt]
  #pragma unroll
  for (int mt = 0; mt < 4; ++mt) {
    const ushort* ar = xb + ((size_t)(g << 10) + mb + (mt << 4) + l16) * DIN;
    #pragma unroll
    for (int kt = 0; kt < 4; ++kt)
      af[mt][kt] = *(const shortx8*)(ar + (kt << 5) + (quad << 3));
  }
  // s for the rows this lane's quad owns: m = mb + mt*16 + quad*4 + r.
  float4 sv[4];
  #pragma unroll
  for (int mt = 0; mt < 4; ++mt)
    sv[mt] = *(const float4*)(s + (size_t)(g << 10) + mb + (mt << 4) + (quad << 2));

  float wsum[4] = {0.f, 0.f, 0.f, 0.f};
  #pragma unroll
  for (int mt = 0; mt < 4; ++mt) {
    floatx4 acc[4] = {{0.f, 0.f, 0.f, 0.f}, {0.f, 0.f, 0.f, 0.f},
                      {0.f, 0.f, 0.f, 0.f}, {0.f, 0.f, 0.f, 0.f}};
    #pragma unroll
    for (int kt = 0; kt < 4; ++kt)
      #pragma unroll
      for (int dt = 0; dt < 4; ++dt)
        acc[dt] = __builtin_amdgcn_mfma_f32_16x16x32_bf16(af[mt][kt],
                                                          bfr[dt][kt],
                                                          acc[dt], 0, 0, 0);
    // bias + relu + s-weight; C layout: row(m) = quad*4+r, col(d) = l16
    #pragma unroll
    for (int dt = 0; dt < 4; ++dt) {
      float bs = 0.f;
      #pragma unroll
      for (int r = 0; r < 4; ++r) {
        const float h = fmaxf(acc[dt][r] + b1v[dt], 0.f);
        bs = fmaf(sv[mt][r], h, bs);
      }
      wsum[dt] += bs;
    }
  }
  #pragma unroll
  for (int dt = 0; dt < 4; ++dt) {
    float w = wsum[dt];
    w += __shfl_xor(w, 16, 64);
    w += __shfl_xor(w, 32, 64);
    if (quad == 0)
      hw_part[(size_t)blk * DH + (wave << 6) + (dt << 4) + l16] = w;
  }
}

// ---------------------------------------------------------------------------
// k3: 256 thr/block; W2 staged to LDS; sum 16 hw partials; GEMV; log_softmax.
// ---------------------------------------------------------------------------
__global__ __launch_bounds__(256) void k3_head(
    const float* __restrict__ hw_part, const float* __restrict__ W2,
    const float* __restrict__ b2, float* __restrict__ out) {
  const int g = blockIdx.x;
  const int t = threadIdx.x;
  __shared__ float w2l[DH * DOUT];   // 2560 floats
  __shared__ float hsum[DH];
  __shared__ float partial[40];
  __shared__ float p[DOUT];
  #pragma unroll
  for (int i = 0; i < (DH * DOUT) / 256; ++i)   // coalesced W2 stage
    w2l[i * 256 + t] = W2[i * 256 + t];
  {
    float hs = 0.f;
    const float* hp = hw_part + (size_t)(g << 4) * DH + t;
    #pragma unroll
    for (int r = 0; r < 16; ++r) hs += hp[r * DH];
    hsum[t] = hs;
  }
  __syncthreads();
  if (t < 40) {
    const int c = t % 10, q = t / 10;
    const float* hg = hsum + q * 64;
    const float* wg = w2l + (q * 64) * DOUT + c;
    float a = 0.f;
    #pragma unroll
    for (int k = 0; k < 64; ++k) a = fmaf(hg[k], wg[k * DOUT], a);
    partial[t] = a;
  }
  __syncthreads();
  if (t < DOUT) {
    p[t] = (partial[t] + partial[t + 10] + partial[t + 20] + partial[t + 30]) *
               (1.0f / N_) + b2[t];
  }
  __syncthreads();
  if (t < DOUT) {
    float mx = p[0];
    #pragma unroll
    for (int c = 1; c < DOUT; ++c) mx = fmaxf(mx, p[c]);
    float se = 0.f;
    #pragma unroll
    for (int c = 0; c < DOUT; ++c) se += expf(p[c] - mx);
    out[g * DOUT + t] = p[t] - (mx + logf(se));
  }
}

extern "C" void kernel_launch(void* const* d_in, const int* in_sizes, int n_in,
                              void* d_out, int out_size, void* d_ws, size_t ws_size,
                              hipStream_t stream) {
  const float* x  = (const float*)d_in[0];
  // d_in[1] = batch (sorted, equal-sized) -> unused
  const float* W1 = (const float*)d_in[2];
  const float* b1 = (const float*)d_in[3];
  const float* W2 = (const float*)d_in[4];
  const float* b2 = (const float*)d_in[5];
  float* out = (float*)d_out;

  // ws (floats): u_part[1024*128] hw_part[1024*256] norminv[65536] s[65536];
  // then bf16 blobs.
  float* u_part  = (float*)d_ws;
  float* hw_part = u_part + 1024 * DIN;
  float* norminv = hw_part + 1024 * DH;
  float* s       = norminv + (size_t)G_ * N_;
  ushort* xb  = (ushort*)(s + (size_t)G_ * N_);         // [65536][128] bf16
  ushort* w1t = xb + (size_t)G_ * N_ * DIN;             // [256][128] bf16

  // Every ws location is written before it is read -> no memset, no atomics.
  k1_fused<<<1024 + 64, 256, 0, stream>>>(x, W1, norminv, u_part, xb, w1t);
  k1b_s<<<1024, 256, 0, stream>>>(xb, norminv, u_part, s);
  k2_mfma<<<1024, 256, 0, stream>>>(xb, w1t, b1, s, hw_part);
  k3_head<<<G_, 256, 0, stream>>>(hw_part, W2, b2, out);
}